// Round 8
// baseline (228.208 us; speedup 1.0000x reference)
//
#include <hip/hip_runtime.h>

typedef __attribute__((ext_vector_type(8))) short bf16x8;
typedef __attribute__((ext_vector_type(4))) float f32x4;
typedef __attribute__((ext_vector_type(8))) unsigned short u16x8;
typedef unsigned long long u64t;
typedef unsigned int u32t;

#define NROWS 65536
#define DDIM  256
#define KCODE 2048

__device__ __forceinline__ unsigned short f2bf_rne(float f) {
  unsigned int u = __builtin_bit_cast(unsigned int, f);
  unsigned int r = (u + 0x7fffu + ((u >> 16) & 1u)) >> 16;
  return (unsigned short)r;
}
__device__ __forceinline__ float bf2f(unsigned short h) {
  unsigned int u = ((unsigned int)h) << 16;
  return __builtin_bit_cast(float, u);
}

typedef const unsigned int __attribute__((address_space(1)))* gp1_t;
typedef unsigned int __attribute__((address_space(3)))* lp3_t;
__device__ __forceinline__ void gload_lds16(const void* g, void* l) {
  __builtin_amdgcn_global_load_lds((gp1_t)g, (lp3_t)l, 16, 0, 0);
}

__device__ __forceinline__ u64t shfl_xor_u64(u64t v, int off) {
  u32t lo = (u32t)v, hi = (u32t)(v >> 32);
  lo = __shfl_xor(lo, off);
  hi = __shfl_xor(hi, off);
  return ((u64t)hi << 32) | lo;
}

// --- prep A: x -> [hi(256)|lo(256)] bf16 per row (overlay on d_out) + ||x||^2 + key init ---
__global__ __launch_bounds__(256) void prep_A(const float* __restrict__ x,
                                              unsigned short* __restrict__ Ap,
                                              float* __restrict__ frow,
                                              u64t* __restrict__ keyArr) {
  const int t   = threadIdx.x;
  const int row = blockIdx.x * 8 + (t >> 5);
  const int d0  = (t & 31) * 8;
  const float* xr = x + (size_t)row * DDIM + d0;
  float4 v0 = *reinterpret_cast<const float4*>(xr);
  float4 v1 = *reinterpret_cast<const float4*>(xr + 4);
  float vv[8] = {v0.x, v0.y, v0.z, v0.w, v1.x, v1.y, v1.z, v1.w};
  u16x8 hi, lo;
  float ss = 0.f;
  #pragma unroll
  for (int i = 0; i < 8; ++i) {
    ss += vv[i] * vv[i];
    unsigned short h = f2bf_rne(vv[i]);
    hi[i] = h;
    lo[i] = f2bf_rne(vv[i] - bf2f(h));
  }
  char* rowp = (char*)Ap + (size_t)row * 1024;
  *reinterpret_cast<u16x8*>(rowp + d0 * 2)       = hi;
  *reinterpret_cast<u16x8*>(rowp + 512 + d0 * 2) = lo;
  #pragma unroll
  for (int off = 16; off; off >>= 1) ss += __shfl_xor(ss, off);
  if ((t & 31) == 0) { frow[row] = ss; keyArr[row] = ~0ull; }
}

// --- prep B: E[d][k] -> Bp[k][512]=[hi(256)|lo(256)] bf16 k-major; enorm; Etg[k][d] fp32 ---
__global__ __launch_bounds__(256) void prep_B(const float* __restrict__ E,
                                              unsigned short* __restrict__ Bp,
                                              float* __restrict__ enorm,
                                              float* __restrict__ Etg) {
  const int k0 = blockIdx.x;
  const int d  = threadIdx.x;
  float v = E[(size_t)d * KCODE + k0];
  Etg[(size_t)k0 * DDIM + d] = v;
  unsigned short h = f2bf_rne(v);
  unsigned short l = f2bf_rne(v - bf2f(h));
  unsigned short* col = Bp + (size_t)k0 * 512;
  col[d] = h; col[256 + d] = l;
  float s = v * v;
  #pragma unroll
  for (int off = 32; off; off >>= 1) s += __shfl_xor(s, off);
  __shared__ float wsum[4];
  if ((threadIdx.x & 63) == 0) wsum[threadIdx.x >> 6] = s;
  __syncthreads();
  if (threadIdx.x == 0) enorm[k0] = (wsum[0] + wsum[1]) + (wsum[2] + wsum[3]);
}

// --- main: distance GEMM over 8 physical K=32 chunks; per chunk stage
// {c_hi,c_lo,x_hi,x_lo} once, compute 3 split-bf16 products (96 MFMA) from it.
// LDS reads per chunk: 24/wave vs 96 MFMA -> MFMA-dominant (was 24 reads/64 MFMA).
// vmcnt(8) at chunk start (never 0 mid-loop): chunk c's loads were issued one
// full chunk (~3700cy) earlier.
__global__ __launch_bounds__(512, 2) void vq_nn(
    const unsigned short* __restrict__ Ap,   // x packed  [row][hi|lo] 1024 B/row
    const unsigned short* __restrict__ Bp,   // codes     [k][hi|lo]   1024 B/code
    const float* __restrict__ enorm,
    const float* __restrict__ frow,
    u64t* __restrict__ keyArr)
{
  extern __shared__ __align__(16) char lds[];   // 2 x 64KB: {ch 16K|cl 16K|xh 16K|xl 16K}

  const int tid = threadIdx.x;
  const int w   = tid >> 6;
  const int l   = tid & 63;
  const int l15 = l & 15;
  const int lg  = l >> 4;
  const int wr  = w >> 2;      // code half (0..1)
  const int wc  = w & 3;       // x-col quarter (0..3)

  // XCD-aware swizzle (kept: FETCH 371->106MB in r7)
  const int xcd = blockIdx.x & 7;
  const int seq = blockIdx.x >> 3;
  const int cb  = seq & 7;                  // code block 0..7
  const int nb  = xcd * 32 + (seq >> 3);    // x-row block 0..255

  // staging map: 512 threads x 16B = 8KB/round; row rl0 = tid>>2, 16B slot (tid&3)*16
  const int rl0  = tid >> 2;                // 0..127
  const int c16  = (tid & 3) * 16;
  const int srcS = c16 ^ (((rl0 >> 1) & 3) << 4);   // pre-swizzled source (involution)
  const char* BpB = (const char*)Bp + (size_t)cb * 256 * 1024;
  const char* ApB = (const char*)Ap + (size_t)nb * 256 * 1024;

  // fcol preload first: oldest vmem ops, drained by first vmcnt(8)
  float fcol[4];
  #pragma unroll
  for (int fc = 0; fc < 4; ++fc)
    fcol[fc] = frow[nb * 256 + wc * 64 + fc * 16 + l15];

  // stage one physical chunk cc: 4 regions x 256 rows x 64B (2 rounds each = 8 gloads)
  auto STAGE = [&](int cc, char* buf) {
    #pragma unroll
    for (int rnd = 0; rnd < 2; ++rnd) {
      const size_t rb = (size_t)(rnd * 128 + rl0) * 1024 + (size_t)cc * 64 + srcS;
      char* dst = buf + rnd * 8192 + w * 1024;   // wave-uniform base + lane*16
      gload_lds16(BpB + rb,       dst);            // c_hi
      gload_lds16(BpB + rb + 512, dst + 16384);    // c_lo
      gload_lds16(ApB + rb,       dst + 32768);    // x_hi
      gload_lds16(ApB + rb + 512, dst + 49152);    // x_lo
    }
  };

  // ds_read addressing: row*64 + (lg*16 ^ ((row>>1 & 3)<<4)); row mod 16 == l15
  const int koX = (lg * 16) ^ ((l15 & 6) << 3);
  int aOff[8];
  #pragma unroll
  for (int fr = 0; fr < 8; ++fr) aOff[fr] = (wr * 128 + fr * 16 + l15) * 64;          // codes
  int bOff[4];
  #pragma unroll
  for (int fc = 0; fc < 4; ++fc) bOff[fc] = 32768 + (wc * 64 + fc * 16 + l15) * 64;   // x

  f32x4 acc[8][4];
  #pragma unroll
  for (int fr = 0; fr < 8; ++fr)
    #pragma unroll
    for (int fc = 0; fc < 4; ++fc) acc[fr][fc] = (f32x4){0.f, 0.f, 0.f, 0.f};

  char* cur = lds;
  char* nxt = lds + 65536;

  STAGE(0, cur);

  for (int c = 0; c < 8; ++c) {
    if (c < 7) {
      STAGE(c + 1, nxt);                                  // 8 loads on top
      asm volatile("s_waitcnt vmcnt(8)" ::: "memory");    // chunk c fully landed
    } else {
      asm volatile("s_waitcnt vmcnt(0)" ::: "memory");    // last chunk drain
    }
    __builtin_amdgcn_s_barrier();                         // publish chunk c

    bf16x8 xh[4], ch[8], cl[8], xl[4];
    #pragma unroll
    for (int fc = 0; fc < 4; ++fc)
      xh[fc] = *reinterpret_cast<const bf16x8*>(cur + bOff[fc] + koX);
    #pragma unroll
    for (int fr = 0; fr < 8; ++fr)
      ch[fr] = *reinterpret_cast<const bf16x8*>(cur + aOff[fr] + koX);

    // P1: c_hi * x_hi
    __builtin_amdgcn_s_setprio(1);
    #pragma unroll
    for (int fr = 0; fr < 8; ++fr)
      #pragma unroll
      for (int fc = 0; fc < 4; ++fc)
        acc[fr][fc] = __builtin_amdgcn_mfma_f32_16x16x32_bf16(ch[fr], xh[fc], acc[fr][fc], 0, 0, 0);
    __builtin_amdgcn_s_setprio(0);

    #pragma unroll
    for (int fr = 0; fr < 8; ++fr)
      cl[fr] = *reinterpret_cast<const bf16x8*>(cur + aOff[fr] + 16384 + koX);

    // P3: c_lo * x_hi   (xh dies after)
    __builtin_amdgcn_s_setprio(1);
    #pragma unroll
    for (int fr = 0; fr < 8; ++fr)
      #pragma unroll
      for (int fc = 0; fc < 4; ++fc)
        acc[fr][fc] = __builtin_amdgcn_mfma_f32_16x16x32_bf16(cl[fr], xh[fc], acc[fr][fc], 0, 0, 0);
    __builtin_amdgcn_s_setprio(0);

    #pragma unroll
    for (int fc = 0; fc < 4; ++fc)
      xl[fc] = *reinterpret_cast<const bf16x8*>(cur + bOff[fc] + 16384 + koX);

    // P2: c_hi * x_lo
    __builtin_amdgcn_s_setprio(1);
    #pragma unroll
    for (int fr = 0; fr < 8; ++fr)
      #pragma unroll
      for (int fc = 0; fc < 4; ++fc)
        acc[fr][fc] = __builtin_amdgcn_mfma_f32_16x16x32_bf16(ch[fr], xl[fc], acc[fr][fc], 0, 0, 0);
    __builtin_amdgcn_s_setprio(0);

    asm volatile("s_waitcnt lgkmcnt(0)" ::: "memory");    // my LDS reads retired
    __builtin_amdgcn_sched_barrier(0);
    __builtin_amdgcn_s_barrier();                         // safe to overwrite cur next iter

    char* tmp = cur; cur = nxt; nxt = tmp;
  }

  // ---- epilogue: dist -> packed u64 key -> fold -> atomicMin per x-row ----
  // C layout: row(code_l) = wr*128 + fr*16 + lg*4 + rg ; col(x_l) = wc*64 + fc*16 + l15
  u64t bk[4] = {~0ull, ~0ull, ~0ull, ~0ull};
  #pragma unroll
  for (int fr = 0; fr < 8; ++fr) {
    const int cbase = cb * 256 + wr * 128 + fr * 16 + lg * 4;
    float4 en4 = *reinterpret_cast<const float4*>(enorm + cbase);
    const float en[4] = {en4.x, en4.y, en4.z, en4.w};
    #pragma unroll
    for (int fc = 0; fc < 4; ++fc)
      #pragma unroll
      for (int rg = 0; rg < 4; ++rg) {
        const float dist = (fcol[fc] + en[rg]) - 2.0f * acc[fr][fc][rg];
        const u64t key = ((u64t)__builtin_bit_cast(u32t, dist) << 32) | (u32t)(cbase + rg);
        if (key < bk[fc]) bk[fc] = key;
      }
  }
  #pragma unroll
  for (int off = 16; off <= 32; off <<= 1)
    #pragma unroll
    for (int fc = 0; fc < 4; ++fc) {
      const u64t o = shfl_xor_u64(bk[fc], off);
      if (o < bk[fc]) bk[fc] = o;
    }
  if (lg == 0) {
    #pragma unroll
    for (int fc = 0; fc < 4; ++fc)
      atomicMin(&keyArr[nb * 256 + wc * 64 + fc * 16 + l15], bk[fc]);
  }
}

// --- gather: key -> code -> out write + loss partial ---
__global__ __launch_bounds__(256) void vq_gather(const u64t* __restrict__ keyArr,
                                                 const float* __restrict__ Etg,
                                                 const float* __restrict__ x,
                                                 float* __restrict__ out,
                                                 float* __restrict__ partial) {
  __shared__ int codes[128];
  __shared__ float lpart[4];
  const int t  = threadIdx.x;
  const int r0 = blockIdx.x * 128;
  if (t < 128) codes[t] = (int)(u32t)keyArr[r0 + t];
  __syncthreads();
  float lsum = 0.f;
  for (int rr = 0; rr < 128; ++rr) {
    const int row  = r0 + rr;
    const int code = codes[rr];
    const float q  = Etg[(size_t)code * DDIM + t];
    const float xv = x[(size_t)row * DDIM + t];
    out[(size_t)row * DDIM + t] = q;
    const float df = q - xv;
    lsum += df * df;
  }
  #pragma unroll
  for (int off = 32; off; off >>= 1) lsum += __shfl_xor(lsum, off);
  if ((t & 63) == 0) lpart[t >> 6] = lsum;
  __syncthreads();
  if (t == 0) partial[blockIdx.x] = (lpart[0] + lpart[1]) + (lpart[2] + lpart[3]);
}

// --- final deterministic loss reduction ---
__global__ __launch_bounds__(256) void vq_final(const float* __restrict__ partial,
                                                float* __restrict__ loss_out) {
  double s = 0.0;
  for (int i = threadIdx.x; i < 512; i += 256) s += (double)partial[i];
  #pragma unroll
  for (int off = 32; off; off >>= 1) s += __shfl_xor(s, off);
  __shared__ double sh[4];
  if ((threadIdx.x & 63) == 0) sh[threadIdx.x >> 6] = s;
  __syncthreads();
  if (threadIdx.x == 0) {
    const double mean = (sh[0] + sh[1] + sh[2] + sh[3]) / 16777216.0;
    loss_out[0] = (float)(0.25 * mean - mean);
  }
}

extern "C" void kernel_launch(void* const* d_in, const int* in_sizes, int n_in,
                              void* d_out, int out_size, void* d_ws, size_t ws_size,
                              hipStream_t stream) {
  const float* x = (const float*)d_in[0];   // [65536, 256]
  const float* E = (const float*)d_in[1];   // [256, 2048]
  float* out = (float*)d_out;
  char*  ws  = (char*)d_ws;

  // ws layout (bytes): keyArr 512K | enorm 8K | frow 256K | partial 2K | Etg 2M | Bp 2M (~4.8 MB)
  u64t*  keyArr  = (u64t*)ws;
  float* enorm   = (float*)(ws + 524288);
  float* frow    = (float*)(ws + 524288 + 8192);
  float* partial = (float*)(ws + 524288 + 8192 + 262144);
  float* Etg     = (float*)(ws + 524288 + 8192 + 262144 + 2048);
  unsigned short* Bp = (unsigned short*)(ws + 524288 + 8192 + 262144 + 2048 + 2097152);

  unsigned short* Ap = (unsigned short*)d_out;   // A' overlay on out (consumed before gather writes)

  hipFuncSetAttribute(reinterpret_cast<const void*>(vq_nn),
                      hipFuncAttributeMaxDynamicSharedMemorySize, 131072);

  prep_A  <<<NROWS / 8, 256, 0, stream>>>(x, Ap, frow, keyArr);
  prep_B  <<<KCODE,     256, 0, stream>>>(E, Bp, enorm, Etg);
  vq_nn   <<<2048,      512, 131072, stream>>>(Ap, Bp, enorm, frow, keyArr);
  vq_gather<<<512,      256, 0, stream>>>(keyArr, Etg, x, out, partial);
  vq_final<<<1,         256, 0, stream>>>(partial, out + (size_t)NROWS * DDIM);
}

// Round 9
// 221.465 us; speedup vs baseline: 1.0305x; 1.0305x over previous
//
#include <hip/hip_runtime.h>

typedef __attribute__((ext_vector_type(8))) short bf16x8;
typedef __attribute__((ext_vector_type(4))) float f32x4;
typedef __attribute__((ext_vector_type(8))) unsigned short u16x8;
typedef unsigned long long u64t;
typedef unsigned int u32t;

#define NROWS 65536
#define DDIM  256
#define KCODE 2048

__device__ __forceinline__ unsigned short f2bf_rne(float f) {
  unsigned int u = __builtin_bit_cast(unsigned int, f);
  unsigned int r = (u + 0x7fffu + ((u >> 16) & 1u)) >> 16;
  return (unsigned short)r;
}
__device__ __forceinline__ float bf2f(unsigned short h) {
  unsigned int u = ((unsigned int)h) << 16;
  return __builtin_bit_cast(float, u);
}

typedef const unsigned int __attribute__((address_space(1)))* gp1_t;
typedef unsigned int __attribute__((address_space(3)))* lp3_t;
__device__ __forceinline__ void gload_lds16(const void* g, void* l) {
  __builtin_amdgcn_global_load_lds((gp1_t)g, (lp3_t)l, 16, 0, 0);
}

__device__ __forceinline__ u64t shfl_xor_u64(u64t v, int off) {
  u32t lo = (u32t)v, hi = (u32t)(v >> 32);
  lo = __shfl_xor(lo, off);
  hi = __shfl_xor(hi, off);
  return ((u64t)hi << 32) | lo;
}

// --- prep A: x -> [hi(256)|lo(256)] bf16 per row (overlay on d_out) + ||x||^2 + key init ---
__global__ __launch_bounds__(256) void prep_A(const float* __restrict__ x,
                                              unsigned short* __restrict__ Ap,
                                              float* __restrict__ frow,
                                              u64t* __restrict__ keyArr) {
  const int t   = threadIdx.x;
  const int row = blockIdx.x * 8 + (t >> 5);
  const int d0  = (t & 31) * 8;
  const float* xr = x + (size_t)row * DDIM + d0;
  float4 v0 = *reinterpret_cast<const float4*>(xr);
  float4 v1 = *reinterpret_cast<const float4*>(xr + 4);
  float vv[8] = {v0.x, v0.y, v0.z, v0.w, v1.x, v1.y, v1.z, v1.w};
  u16x8 hi, lo;
  float ss = 0.f;
  #pragma unroll
  for (int i = 0; i < 8; ++i) {
    ss += vv[i] * vv[i];
    unsigned short h = f2bf_rne(vv[i]);
    hi[i] = h;
    lo[i] = f2bf_rne(vv[i] - bf2f(h));
  }
  char* rowp = (char*)Ap + (size_t)row * 1024;
  *reinterpret_cast<u16x8*>(rowp + d0 * 2)       = hi;
  *reinterpret_cast<u16x8*>(rowp + 512 + d0 * 2) = lo;
  #pragma unroll
  for (int off = 16; off; off >>= 1) ss += __shfl_xor(ss, off);
  if ((t & 31) == 0) { frow[row] = ss; keyArr[row] = ~0ull; }
}

// --- prep B: E[d][k] -> Bp[k][512]=[hi(256)|lo(256)] bf16 k-major; enorm; Etg[k][d] fp32 ---
__global__ __launch_bounds__(256) void prep_B(const float* __restrict__ E,
                                              unsigned short* __restrict__ Bp,
                                              float* __restrict__ enorm,
                                              float* __restrict__ Etg) {
  const int k0 = blockIdx.x;
  const int d  = threadIdx.x;
  float v = E[(size_t)d * KCODE + k0];
  Etg[(size_t)k0 * DDIM + d] = v;
  unsigned short h = f2bf_rne(v);
  unsigned short l = f2bf_rne(v - bf2f(h));
  unsigned short* col = Bp + (size_t)k0 * 512;
  col[d] = h; col[256 + d] = l;
  float s = v * v;
  #pragma unroll
  for (int off = 32; off; off >>= 1) s += __shfl_xor(s, off);
  __shared__ float wsum[4];
  if ((threadIdx.x & 63) == 0) wsum[threadIdx.x >> 6] = s;
  __syncthreads();
  if (threadIdx.x == 0) enorm[k0] = (wsum[0] + wsum[1]) + (wsum[2] + wsum[3]);
}

// --- main: distance GEMM over 8 physical K=32 chunks, m201-style 6-phase
// schedule per chunk. Phase = {reads | stage | (vmcnt) | SB | lgkm(0) |
// prio1 16xMFMA prio0 | SB}. Issue order per chunk: xh,ch,cl,xl (2 each);
// counted waits at ph1 vmcnt(6), ph3 vmcnt(6), ph5 vmcnt(4) publish the
// data consumed by the NEXT phase's pre-barrier reads. Never vmcnt(0)
// mid-loop; every load gets >=4 phases of latency budget.
__global__ __launch_bounds__(512, 2) void vq_nn(
    const unsigned short* __restrict__ Ap,   // x packed  [row][hi|lo] 1024 B/row
    const unsigned short* __restrict__ Bp,   // codes     [k][hi|lo]   1024 B/code
    const float* __restrict__ enorm,
    const float* __restrict__ frow,
    u64t* __restrict__ keyArr)
{
  extern __shared__ __align__(16) char lds[];   // 2 x 64KB: {ch 16K|cl 16K|xh 16K|xl 16K}

  const int tid = threadIdx.x;
  const int w   = tid >> 6;
  const int l   = tid & 63;
  const int l15 = l & 15;
  const int lg  = l >> 4;
  const int wr  = w >> 2;      // code half (0..1)
  const int wc  = w & 3;       // x-col quarter (0..3)

  // XCD-aware swizzle (FETCH 371->106MB, r7)
  const int xcd = blockIdx.x & 7;
  const int seq = blockIdx.x >> 3;
  const int cb  = seq & 7;                  // code block 0..7
  const int nb  = xcd * 32 + (seq >> 3);    // x-row block 0..255

  const int rl0  = tid >> 2;                // 0..127
  const int c16  = (tid & 3) * 16;
  const int srcS = c16 ^ (((rl0 >> 1) & 3) << 4);   // pre-swizzled source (involution)
  const char* BpB = (const char*)Bp + (size_t)cb * 256 * 1024;
  const char* ApB = (const char*)Ap + (size_t)nb * 256 * 1024;

  // fcol preload first: oldest vmem ops, drained by prologue vmcnt(4)
  float fcol[4];
  #pragma unroll
  for (int fc = 0; fc < 4; ++fc)
    fcol[fc] = frow[nb * 256 + wc * 64 + fc * 16 + l15];

  // stage one region-round: 512 thr x 16B = 8KB (half a 16KB region)
  auto ST = [&](char* buf, int roff, const char* src, int rnd, int cc, int hl) {
    gload_lds16(src + (size_t)(rnd * 128 + rl0) * 1024 + (size_t)cc * 64 + hl + srcS,
                buf + roff + rnd * 8192 + w * 1024);
  };
  // regions: ch=+0 (src BpB,+0) | cl=+16384 (BpB,+512) | xh=+32768 (ApB,+0) | xl=+49152 (ApB,+512)

  const int koX = (lg * 16) ^ ((l15 & 6) << 3);
  int aOff[8];
  #pragma unroll
  for (int fr = 0; fr < 8; ++fr) aOff[fr] = (wr * 128 + fr * 16 + l15) * 64;          // codes
  int bOff[4];
  #pragma unroll
  for (int fc = 0; fc < 4; ++fc) bOff[fc] = 32768 + (wc * 64 + fc * 16 + l15) * 64;   // x

  f32x4 acc[8][4];
  #pragma unroll
  for (int fr = 0; fr < 8; ++fr)
    #pragma unroll
    for (int fc = 0; fc < 4; ++fc) acc[fr][fc] = (f32x4){0.f, 0.f, 0.f, 0.f};

  bf16x8 ch[8], cl[4], xh[4], xl[4];

#define MM(av, a0, bv)                                                        \
  __builtin_amdgcn_s_setprio(1);                                              \
  _Pragma("unroll")                                                           \
  for (int i_ = 0; i_ < 4; ++i_)                                              \
    _Pragma("unroll")                                                         \
    for (int j_ = 0; j_ < 4; ++j_)                                            \
      acc[(a0) + i_][j_] = __builtin_amdgcn_mfma_f32_16x16x32_bf16(           \
          (av)[i_], (bv)[j_], acc[(a0) + i_][j_], 0, 0, 0);                   \
  __builtin_amdgcn_s_setprio(0);

#define SB  __builtin_amdgcn_s_barrier()
#define LGK asm volatile("s_waitcnt lgkmcnt(0)" ::: "memory")

  char* cur = lds;
  char* nxt = lds + 65536;

  // prologue: chunk 0 in canonical issue order xh,ch,cl,xl; publish xh+ch
  ST(cur, 32768, ApB, 0, 0, 0);   ST(cur, 32768, ApB, 1, 0, 0);     // xh
  ST(cur, 0,     BpB, 0, 0, 0);   ST(cur, 0,     BpB, 1, 0, 0);     // ch
  ST(cur, 16384, BpB, 0, 0, 512); ST(cur, 16384, BpB, 1, 0, 512);   // cl
  ST(cur, 49152, ApB, 0, 0, 512); ST(cur, 49152, ApB, 1, 0, 512);   // xl
  asm volatile("s_waitcnt vmcnt(4)" ::: "memory");                  // xh,ch landed
  SB;

  for (int c = 0; c < 8; ++c) {
    const bool pref = (c < 7);

    // ---- ph0: read xh + ch[0..3] (published last phase); stage (c+1).xh ----
    #pragma unroll
    for (int j = 0; j < 4; ++j) xh[j] = *(const bf16x8*)(cur + bOff[j] + koX);
    #pragma unroll
    for (int i = 0; i < 4; ++i) ch[i] = *(const bf16x8*)(cur + aOff[i] + koX);
    if (pref) { ST(nxt, 32768, ApB, 0, c + 1, 0); ST(nxt, 32768, ApB, 1, c + 1, 0); }
    SB; LGK;
    MM(ch, 0, xh);                       // acc[0..3] += ch_h0 x xh
    SB;

    // ---- ph1: read ch[4..7]; stage (c+1).ch; publish c.cl ----
    #pragma unroll
    for (int i = 0; i < 4; ++i) ch[4 + i] = *(const bf16x8*)(cur + aOff[4 + i] + koX);
    if (pref) {
      ST(nxt, 0, BpB, 0, c + 1, 0); ST(nxt, 0, BpB, 1, c + 1, 0);
      asm volatile("s_waitcnt vmcnt(6)" ::: "memory");   // leaves c.xl2 + (c+1).xh2,ch2
    } else {
      asm volatile("s_waitcnt vmcnt(2)" ::: "memory");   // leaves c.xl2
    }
    SB; LGK;
    MM(ch + 4, 4, xh);                   // acc[4..7] += ch_h1 x xh
    SB;

    // ---- ph2: read cl_h0; stage (c+1).cl rnd0 ----
    #pragma unroll
    for (int i = 0; i < 4; ++i) cl[i] = *(const bf16x8*)(cur + aOff[i] + 16384 + koX);
    if (pref) ST(nxt, 16384, BpB, 0, c + 1, 512);
    SB; LGK;
    MM(cl, 0, xh);                       // acc[0..3] += cl_h0 x xh
    SB;

    // ---- ph3: read cl_h1; stage (c+1).cl rnd1; publish c.xl ----
    #pragma unroll
    for (int i = 0; i < 4; ++i) cl[i] = *(const bf16x8*)(cur + aOff[4 + i] + 16384 + koX);
    if (pref) {
      ST(nxt, 16384, BpB, 1, c + 1, 512);
      asm volatile("s_waitcnt vmcnt(6)" ::: "memory");   // leaves (c+1).xh2,ch2,cl2
    } else {
      asm volatile("s_waitcnt vmcnt(0)" ::: "memory");   // last chunk: drain c.xl
    }
    SB; LGK;
    MM(cl, 4, xh);                       // acc[4..7] += cl_h1 x xh
    SB;

    // ---- ph4: read xl; stage (c+1).xl rnd0 ----
    #pragma unroll
    for (int j = 0; j < 4; ++j) xl[j] = *(const bf16x8*)(cur + bOff[j] + 16384 + koX);
    if (pref) ST(nxt, 49152, ApB, 0, c + 1, 512);
    SB; LGK;
    MM(ch, 0, xl);                       // acc[0..3] += ch_h0 x xl
    SB;

    // ---- ph5: stage (c+1).xl rnd1; publish (c+1).xh+ch for next ph0 ----
    if (pref) {
      ST(nxt, 49152, ApB, 1, c + 1, 512);
      asm volatile("s_waitcnt vmcnt(4)" ::: "memory");   // leaves (c+1).cl2,xl2
    }
    SB; LGK;
    MM(ch + 4, 4, xl);                   // acc[4..7] += ch_h1 x xl
    SB;

    char* tmp = cur; cur = nxt; nxt = tmp;
  }

#undef MM
#undef SB
#undef LGK

  // ---- epilogue: dist -> packed u64 key -> fold -> atomicMin per x-row ----
  // C layout: row(code_l) = wr*128 + fr*16 + lg*4 + rg ; col(x_l) = wc*64 + fc*16 + l15
  u64t bk[4] = {~0ull, ~0ull, ~0ull, ~0ull};
  #pragma unroll
  for (int fr = 0; fr < 8; ++fr) {
    const int cbase = cb * 256 + wr * 128 + fr * 16 + lg * 4;
    float4 en4 = *reinterpret_cast<const float4*>(enorm + cbase);
    const float en[4] = {en4.x, en4.y, en4.z, en4.w};
    #pragma unroll
    for (int fc = 0; fc < 4; ++fc)
      #pragma unroll
      for (int rg = 0; rg < 4; ++rg) {
        const float dist = (fcol[fc] + en[rg]) - 2.0f * acc[fr][fc][rg];
        const u64t key = ((u64t)__builtin_bit_cast(u32t, dist) << 32) | (u32t)(cbase + rg);
        if (key < bk[fc]) bk[fc] = key;
      }
  }
  #pragma unroll
  for (int off = 16; off <= 32; off <<= 1)
    #pragma unroll
    for (int fc = 0; fc < 4; ++fc) {
      const u64t o = shfl_xor_u64(bk[fc], off);
      if (o < bk[fc]) bk[fc] = o;
    }
  if (lg == 0) {
    #pragma unroll
    for (int fc = 0; fc < 4; ++fc)
      atomicMin(&keyArr[nb * 256 + wc * 64 + fc * 16 + l15], bk[fc]);
  }
}

// --- gather: key -> code -> out write + loss partial ---
__global__ __launch_bounds__(256) void vq_gather(const u64t* __restrict__ keyArr,
                                                 const float* __restrict__ Etg,
                                                 const float* __restrict__ x,
                                                 float* __restrict__ out,
                                                 float* __restrict__ partial) {
  __shared__ int codes[128];
  __shared__ float lpart[4];
  const int t  = threadIdx.x;
  const int r0 = blockIdx.x * 128;
  if (t < 128) codes[t] = (int)(u32t)keyArr[r0 + t];
  __syncthreads();
  float lsum = 0.f;
  for (int rr = 0; rr < 128; ++rr) {
    const int row  = r0 + rr;
    const int code = codes[rr];
    const float q  = Etg[(size_t)code * DDIM + t];
    const float xv = x[(size_t)row * DDIM + t];
    out[(size_t)row * DDIM + t] = q;
    const float df = q - xv;
    lsum += df * df;
  }
  #pragma unroll
  for (int off = 32; off; off >>= 1) lsum += __shfl_xor(lsum, off);
  if ((t & 63) == 0) lpart[t >> 6] = lsum;
  __syncthreads();
  if (t == 0) partial[blockIdx.x] = (lpart[0] + lpart[1]) + (lpart[2] + lpart[3]);
}

// --- final deterministic loss reduction ---
__global__ __launch_bounds__(256) void vq_final(const float* __restrict__ partial,
                                                float* __restrict__ loss_out) {
  double s = 0.0;
  for (int i = threadIdx.x; i < 512; i += 256) s += (double)partial[i];
  #pragma unroll
  for (int off = 32; off; off >>= 1) s += __shfl_xor(s, off);
  __shared__ double sh[4];
  if ((threadIdx.x & 63) == 0) sh[threadIdx.x >> 6] = s;
  __syncthreads();
  if (threadIdx.x == 0) {
    const double mean = (sh[0] + sh[1] + sh[2] + sh[3]) / 16777216.0;
    loss_out[0] = (float)(0.25 * mean - mean);
  }
}

extern "C" void kernel_launch(void* const* d_in, const int* in_sizes, int n_in,
                              void* d_out, int out_size, void* d_ws, size_t ws_size,
                              hipStream_t stream) {
  const float* x = (const float*)d_in[0];   // [65536, 256]
  const float* E = (const float*)d_in[1];   // [256, 2048]
  float* out = (float*)d_out;
  char*  ws  = (char*)d_ws;

  // ws layout (bytes): keyArr 512K | enorm 8K | frow 256K | partial 2K | Etg 2M | Bp 2M (~4.8 MB)
  u64t*  keyArr  = (u64t*)ws;
  float* enorm   = (float*)(ws + 524288);
  float* frow    = (float*)(ws + 524288 + 8192);
  float* partial = (float*)(ws + 524288 + 8192 + 262144);
  float* Etg     = (float*)(ws + 524288 + 8192 + 262144 + 2048);
  unsigned short* Bp = (unsigned short*)(ws + 524288 + 8192 + 262144 + 2048 + 2097152);

  unsigned short* Ap = (unsigned short*)d_out;   // A' overlay on out (consumed before gather writes)

  hipFuncSetAttribute(reinterpret_cast<const void*>(vq_nn),
                      hipFuncAttributeMaxDynamicSharedMemorySize, 131072);

  prep_A  <<<NROWS / 8, 256, 0, stream>>>(x, Ap, frow, keyArr);
  prep_B  <<<KCODE,     256, 0, stream>>>(E, Bp, enorm, Etg);
  vq_nn   <<<2048,      512, 131072, stream>>>(Ap, Bp, enorm, frow, keyArr);
  vq_gather<<<512,      256, 0, stream>>>(keyArr, Etg, x, out, partial);
  vq_final<<<1,         256, 0, stream>>>(partial, out + (size_t)NROWS * DDIM);
}